// Round 10
// baseline (122.886 us; speedup 1.0000x reference)
//
#include <hip/hip_runtime.h>

#define HD 128
#define LSEQ 200
#define BATCH 2048
#define NE 8
#define SWH 64

#define BM 32        // tokens per tile
#define LDX 136      // padded bf16 row stride for x tile
#define LDH 264      // padded bf16 row stride for hidden tile
#define NTILES ((BATCH * LSEQ) / BM)   // 12800
#define GRID 512     // persistent: 2 blocks/CU (512 threads -> 16 waves/CU)

typedef float f32x4 __attribute__((ext_vector_type(4)));
typedef __bf16 bf16x4 __attribute__((ext_vector_type(4)));
typedef __bf16 bf16x8 __attribute__((ext_vector_type(8)));

// Raw barrier: per-wave LDS drain + s_barrier, no vmcnt(0) drain.
#define BAR() do {                                          \
    asm volatile("s_waitcnt lgkmcnt(0)" ::: "memory");      \
    __builtin_amdgcn_sched_barrier(0);                      \
    __builtin_amdgcn_s_barrier();                           \
    __builtin_amdgcn_sched_barrier(0);                      \
} while (0)

static __device__ __forceinline__ bf16x8 cvt8(const float* p) {
    float4 a = *(const float4*)p;
    float4 b = *(const float4*)(p + 4);
    bf16x8 r;
    r[0] = (__bf16)a.x; r[1] = (__bf16)a.y; r[2] = (__bf16)a.z; r[3] = (__bf16)a.w;
    r[4] = (__bf16)b.x; r[5] = (__bf16)b.y; r[6] = (__bf16)b.z; r[7] = (__bf16)b.w;
    return r;
}

// ================= single fused kernel =================
// Phase 0: routing (every block, redundant & deterministic)
// Phase 1: weight fragments f32 -> bf16 regs, straight from source tensors
// Phase 2: persistent tile loop (identical GEMM structure to R8)
__global__ __launch_bounds__(512, 4)
void moe_all(const float* __restrict__ x,
             const float* __restrict__ x_real,
             const float* __restrict__ uW1, const float* __restrict__ ub1,
             const float* __restrict__ uW2, const float* __restrict__ ub2,
             const float* __restrict__ eW1, const float* __restrict__ eb1,
             const float* __restrict__ eW2, const float* __restrict__ eb2,
             const float* __restrict__ sW1, const float* __restrict__ sb1,
             const float* __restrict__ sW2, const float* __restrict__ sb2,
             float* __restrict__ out) {
    __shared__ __align__(16) unsigned short xs[BM * LDX];  //  8704 B
    __shared__ __align__(16) unsigned short hs[BM * LDH];  // 16896 B
    __shared__ float part[512];
    __shared__ float xm[HD];
    __shared__ float hmid[SWH];
    __shared__ float logits[NE];
    __shared__ int route_s;

    const int t = threadIdx.x;     // 0..511
    const int lane = t & 63;
    const int w = t >> 6;          // wave 0..7
    const int l16 = lane & 15;
    const int lq = lane >> 4;      // quadrant 0..3
    const int ncb = w * 32;        // GEMM1: this wave's 32 hidden cols
    const int ncb2 = w * 16;       // GEMM2: this wave's 16 output cols

    // ---------- phase 0: routing ----------
    { // mean over sequence: 4 quarter-sums per column, coalesced
        int col = t & 127, q = t >> 7;
        float s = 0.f;
        for (int l = q * 50; l < q * 50 + 50; ++l) s += x_real[l * HD + col];
        part[t] = s;
    }
    __syncthreads();
    if (t < HD) xm[t] = (part[t] + part[t + 128] + part[t + 256] + part[t + 384]) * (1.0f / LSEQ);
    __syncthreads();
    { // switch layer 1: wave w computes hidden units w*8 .. w*8+7
        const float2* xm2 = (const float2*)xm;
        float2 xv = xm2[lane];
#pragma unroll
        for (int jj = 0; jj < 8; ++jj) {
            int j = w * 8 + jj;
            float2 wv = *(const float2*)&sW1[j * HD + lane * 2];
            float p = wv.x * xv.x + wv.y * xv.y;
            p += __shfl_xor(p, 1);  p += __shfl_xor(p, 2);  p += __shfl_xor(p, 4);
            p += __shfl_xor(p, 8);  p += __shfl_xor(p, 16); p += __shfl_xor(p, 32);
            if (lane == 0) hmid[j] = fmaxf(p + sb1[j], 0.f);
        }
    }
    __syncthreads();
    if (w == 0) { // switch layer 2: 8-lane group per logit
        int e = lane >> 3, k0 = (lane & 7) * 8;
        float s = 0.f;
#pragma unroll
        for (int k = 0; k < 8; ++k) s += sW2[e * SWH + k0 + k] * hmid[k0 + k];
        s += __shfl_xor(s, 1); s += __shfl_xor(s, 2); s += __shfl_xor(s, 4);
        if ((lane & 7) == 0) logits[e] = s + sb2[e];
    }
    __syncthreads();
    if (t == 0) {
        float mx = logits[0]; int am = 0;
        for (int e = 1; e < NE; ++e) if (logits[e] > mx) { mx = logits[e]; am = e; }
        float den = 0.f;
        for (int e = 0; e < NE; ++e) den += __expf(logits[e] - mx);
        route_s = am;
        if (blockIdx.x == 0) {
            out[(size_t)BATCH * LSEQ * HD + 0] = (float)am;   // route
            out[(size_t)BATCH * LSEQ * HD + 1] = 1.0f / den;  // out_prob_max
        }
    }
    __syncthreads();
    const int r = route_s;

    // ---------- phase 1: weight fragments straight from f32 sources ----------
    // W1cat row hc: hc<128 -> uW1[hc], else eW1[r][hc-128]. Waves 0-3: uW1, waves 4-7: eW1.
    const float* w1src = (w < 4) ? &uW1[(ncb + l16) * HD]
                                 : &eW1[((size_t)r * HD + (ncb - HD + l16)) * HD];
    bf16x8 w1[4][2];   // [ks][ht]
#pragma unroll
    for (int ks = 0; ks < 4; ++ks)
#pragma unroll
        for (int ht = 0; ht < 2; ++ht)
            w1[ks][ht] = cvt8(w1src + (ht * 16) * HD + ks * 32 + lq * 8);
    // W2cat col k for out-row oc: k<128 -> uW2[oc][k], else eW2[r][oc][k-128]. ks<4: uW2, ks>=4: eW2.
    const int oc = ncb2 + l16;
    bf16x8 w2[8];      // [ks]
#pragma unroll
    for (int ks = 0; ks < 4; ++ks)
        w2[ks] = cvt8(&uW2[oc * HD + ks * 32 + lq * 8]);
#pragma unroll
    for (int ks = 4; ks < 8; ++ks)
        w2[ks] = cvt8(&eW2[((size_t)r * HD + oc) * HD + (ks - 4) * 32 + lq * 8]);

    f32x4 bias1v[2], bias2v;
#pragma unroll
    for (int ht = 0; ht < 2; ++ht) {
        int hc2 = ncb + ht * 16 + lq * 4;
        bias1v[ht] = (w < 4) ? *(const f32x4*)&ub1[hc2]
                             : *(const f32x4*)&eb1[r * HD + hc2 - HD];
    }
    {
        int oc2 = ncb2 + lq * 4;
        f32x4 bu = *(const f32x4*)&ub2[oc2];
        f32x4 be = *(const f32x4*)&eb2[r * HD + oc2];
        bias2v = bu + be;
    }

    // ---------- phase 2: persistent tile loop (R8 structure, depth-2 prefetch) ----------
    const int srow0 = t >> 5;            // staging row 0..15
    const int sc4 = (t & 31) * 4;

    const int t0 = blockIdx.x;
    float4 pvA[2], pvB[2];
    { // prologue: pvA <- t0, pvB <- t0+GRID
        const float4* x4 = (const float4*)(x + (size_t)t0 * (BM * HD));
#pragma unroll
        for (int i = 0; i < 2; ++i) pvA[i] = x4[t + i * 512];
        if (t0 + GRID < NTILES) {
            const float4* x4b = (const float4*)(x + (size_t)(t0 + GRID) * (BM * HD));
#pragma unroll
            for (int i = 0; i < 2; ++i) pvB[i] = x4b[t + i * 512];
        }
    }

#define ITER(PV, TILE) do {                                                     \
        /* stage xs <- PV (f32->bf16 packed b64) */                             \
        _Pragma("unroll")                                                       \
        for (int i = 0; i < 2; ++i) {                                           \
            bf16x4 b;                                                           \
            b[0] = (__bf16)PV[i].x; b[1] = (__bf16)PV[i].y;                     \
            b[2] = (__bf16)PV[i].z; b[3] = (__bf16)PV[i].w;                     \
            *(bf16x4*)&xs[(srow0 + i * 16) * LDX + sc4] = b;                    \
        }                                                                       \
        /* refill PV <- TILE+2*GRID (in flight for 2 iterations) */             \
        if ((TILE) + 2 * GRID < NTILES) {                                       \
            const float4* x4n = (const float4*)(x + (size_t)((TILE) + 2 * GRID) * (BM * HD)); \
            _Pragma("unroll")                                                   \
            for (int i = 0; i < 2; ++i) PV[i] = x4n[t + i * 512];               \
        }                                                                       \
        BAR();   /* xs ready */                                                 \
        f32x4 acc1[2][2] = {};                                                  \
        _Pragma("unroll")                                                       \
        for (int ks = 0; ks < 4; ++ks) {                                        \
            const int kofs = ks * 32 + lq * 8;                                  \
            bf16x8 xf[2];                                                       \
            _Pragma("unroll")                                                   \
            for (int tt = 0; tt < 2; ++tt)                                      \
                xf[tt] = *(const bf16x8*)&xs[(tt * 16 + l16) * LDX + kofs];     \
            _Pragma("unroll")                                                   \
            for (int ht = 0; ht < 2; ++ht)                                      \
                _Pragma("unroll")                                               \
                for (int tt = 0; tt < 2; ++tt)                                  \
                    acc1[ht][tt] = __builtin_amdgcn_mfma_f32_16x16x32_bf16(     \
                        w1[ks][ht], xf[tt], acc1[ht][tt], 0, 0, 0);             \
        }                                                                       \
        _Pragma("unroll")                                                       \
        for (int ht = 0; ht < 2; ++ht)                                          \
            _Pragma("unroll")                                                   \
            for (int tt = 0; tt < 2; ++tt) {                                    \
                bf16x4 hv;                                                      \
                _Pragma("unroll")                                               \
                for (int rr = 0; rr < 4; ++rr) {                                \
                    float v = acc1[ht][tt][rr] + bias1v[ht][rr];                \
                    hv[rr] = (__bf16)(v > 0.f ? v : 0.f);                       \
                }                                                               \
                *(bf16x4*)&hs[(tt * 16 + l16) * LDH + ncb + ht * 16 + lq * 4] = hv; \
            }                                                                   \
        BAR();   /* hs ready */                                                 \
        f32x4 acc2[2] = {};                                                     \
        _Pragma("unroll")                                                       \
        for (int ks = 0; ks < 8; ++ks) {                                        \
            const int kofs = ks * 32 + lq * 8;                                  \
            bf16x8 hf[2];                                                       \
            _Pragma("unroll")                                                   \
            for (int tt = 0; tt < 2; ++tt)                                      \
                hf[tt] = *(const bf16x8*)&hs[(tt * 16 + l16) * LDH + kofs];     \
            _Pragma("unroll")                                                   \
            for (int tt = 0; tt < 2; ++tt)                                      \
                acc2[tt] = __builtin_amdgcn_mfma_f32_16x16x32_bf16(             \
                    w2[ks], hf[tt], acc2[tt], 0, 0, 0);                         \
        }                                                                       \
        float* outp = out + (size_t)(TILE) * (BM * HD);                         \
        _Pragma("unroll")                                                       \
        for (int tt = 0; tt < 2; ++tt) {                                        \
            f32x4 o;                                                            \
            _Pragma("unroll")                                                   \
            for (int rr = 0; rr < 4; ++rr) o[rr] = acc2[tt][rr] + bias2v[rr];   \
            *(f32x4*)&outp[(size_t)(tt * 16 + l16) * HD + ncb2 + lq * 4] = o;   \
        }                                                                       \
    } while (0)

    int tile = t0;
    while (tile < NTILES) {
        ITER(pvA, tile);
        tile += GRID;
        if (tile >= NTILES) break;
        ITER(pvB, tile);
        tile += GRID;
    }
#undef ITER
}

extern "C" void kernel_launch(void* const* d_in, const int* in_sizes, int n_in,
                              void* d_out, int out_size, void* d_ws, size_t ws_size,
                              hipStream_t stream) {
    const float* x      = (const float*)d_in[0];
    const float* x_real = (const float*)d_in[1];
    // d_in[2] = user_embedding (unused by reference)
    const float* uW1 = (const float*)d_in[3];
    const float* ub1 = (const float*)d_in[4];
    const float* uW2 = (const float*)d_in[5];
    const float* ub2 = (const float*)d_in[6];
    const float* eW1 = (const float*)d_in[7];
    const float* eb1 = (const float*)d_in[8];
    const float* eW2 = (const float*)d_in[9];
    const float* eb2 = (const float*)d_in[10];
    const float* sW1 = (const float*)d_in[11];
    const float* sb1 = (const float*)d_in[12];
    const float* sW2 = (const float*)d_in[13];
    const float* sb2 = (const float*)d_in[14];
    float* out = (float*)d_out;

    moe_all<<<GRID, 512, 0, stream>>>(x, x_real,
                                      uW1, ub1, uW2, ub2,
                                      eW1, eb1, eW2, eb2,
                                      sW1, sb1, sW2, sb2,
                                      out);
}